// Round 5
// baseline (1515.469 us; speedup 1.0000x reference)
//
#include <hip/hip_runtime.h>

typedef __attribute__((ext_vector_type(4))) float f32x4;
typedef __attribute__((ext_vector_type(8))) short short8;

#define LN_EPS 1e-5f

__device__ __forceinline__ float bf2f(short x) {
  union { unsigned u; float f; } c;
  c.u = ((unsigned)(unsigned short)x) << 16;
  return c.f;
}
__device__ __forceinline__ short f2b(float f) {
  union { float f; unsigned u; } c; c.f = f;
  unsigned r = (c.u + 0x7fffu + ((c.u >> 16) & 1u)) >> 16;
  return (short)r;
}

// ---------------- f32 -> bf16 convert (8 elems / thread) ----------------
__global__ __launch_bounds__(256) void cvt_kernel(const float* __restrict__ src,
                                                  short* __restrict__ dst, int n8) {
  int idx = blockIdx.x * 256 + threadIdx.x;
  int stride = gridDim.x * 256;
  for (int c = idx; c < n8; c += stride) {
    const f32x4* s = (const f32x4*)(src + (size_t)c * 8);
    f32x4 v0 = s[0], v1 = s[1];
    short8 o;
    o[0] = f2b(v0.x); o[1] = f2b(v0.y); o[2] = f2b(v0.z); o[3] = f2b(v0.w);
    o[4] = f2b(v1.x); o[5] = f2b(v1.y); o[6] = f2b(v1.z); o[7] = f2b(v1.w);
    *(short8*)(dst + (size_t)c * 8) = o;
  }
}

__global__ __launch_bounds__(256) void pack_bias(const float* __restrict__ bq,
                                                 const float* __restrict__ bk,
                                                 const float* __restrict__ bv,
                                                 float* __restrict__ dst) {
  int t = blockIdx.x * 256 + threadIdx.x;
  if (t < 1024) { dst[t] = bq[t]; dst[1024 + t] = bk[t]; dst[2048 + t] = bv[t]; }
}

__device__ __forceinline__ void gload16(const short* g, const short* l) {
  __builtin_amdgcn_global_load_lds((const __attribute__((address_space(1))) unsigned int*)g,
                                   (__attribute__((address_space(3))) unsigned int*)l,
                                   16, 0, 0);
}

// ---------------- GEMM: C[M,N] = A[M,1024] * W[N,1024]^T (+ epilogue) ----------------
// m201-style 8-phase schedule: 256x256 tile, 2 K-tiles (BK=64) per iter, 8 iters.
// 512 threads (8 waves 2Mx4N). LDS 128KB: A{buf0,buf1} + B{buf0,buf1}, each 16KB.
// Per phase: {ds_reads | stage 1 half-tile (2 gload16)} -> pre-MFMA barrier ->
// lgkmcnt(0)+sched_barrier -> setprio(1) 16 MFMA setprio(0) -> end barrier.
// Stage ring: P1/2->B(2t+1), P3/4->A(2t+2), P5/6->B(2t+2), P7/8->A(2t+3).
// Counted waits: vmcnt(4) at P4 and P8 only (2 newest stage-slots may fly).
// XOR-8 chunk swizzle: phys 16B-chunk = logical ^ (row&7); inverse on global src.
template <int MODE>  // 0: out bf16 ldc=N, bias   1: out f32 ldc=N, bias+resid
__global__ __launch_bounds__(512, 2) void gemm256(
    const short* __restrict__ A, const short* __restrict__ W,
    const float* __restrict__ bias, const float* __restrict__ resid,
    void* __restrict__ Cptr, int N) {
  __shared__ __align__(16) short lds[65536];  // A0:0 A1:16384 B0:32768 B1:49152

  const int tid = threadIdx.x;
  const int w = tid >> 6, l = tid & 63;
  const int wr = w >> 2, wc = w & 3;
  const int r0 = l & 15, hk = l >> 4;

  // XCD swizzle (grid % 8 == 0 here)
  const int q8 = gridDim.x >> 3;
  const int wg = (blockIdx.x & 7) * q8 + (blockIdx.x >> 3);
  const int nbx = N >> 8;
  const int mb = wg / nbx, nb = wg - mb * nbx;
  const int m0 = mb << 8, n0 = nb << 8;

  // staging: half-tile = 128 rows x 64 shorts (16KB); thread covers 16B chunks
  // tid (rows 0..63) and tid+512 (rows 64..127); phys chunk tid&7, row srow.
  const int srow = tid >> 3;
  const int colsh = (((tid & 7) ^ (srow & 7)) << 3);  // inv-swizzled col (shorts)
  const short* gA = A + (size_t)(m0 + srow) * 1024 + colsh;
  const short* gB = W + (size_t)(n0 + srow) * 1024 + colsh;
  const int wofs = w * 512;  // wave-uniform LDS dest (shorts); lane*16B added by HW

#define STAGE(gbase, ldsbase, half, kt) do {                                   \
    const short* g_ = (gbase) + (size_t)(half) * 131072 + (size_t)(kt) * 64;   \
    gload16(g_,         &lds[(ldsbase) + (half) * 8192 + wofs]);               \
    gload16(g_ + 65536, &lds[(ldsbase) + (half) * 8192 + 4096 + wofs]);        \
  } while (0)

#define PRE_MFMA_BARRIER() do {                                                \
    __builtin_amdgcn_sched_barrier(0);                                         \
    __builtin_amdgcn_s_barrier();                                              \
    __builtin_amdgcn_sched_barrier(0);                                         \
    asm volatile("s_waitcnt lgkmcnt(0)" ::: "memory");                         \
    __builtin_amdgcn_sched_barrier(0);                                         \
  } while (0)

#define END_BARRIER() do {                                                     \
    __builtin_amdgcn_sched_barrier(0);                                         \
    __builtin_amdgcn_s_barrier();                                              \
    __builtin_amdgcn_sched_barrier(0);                                         \
  } while (0)

#define MFMA_BLK(AV, B0V, B1V, J0, J1) do {                                    \
    __builtin_amdgcn_s_setprio(1);                                             \
    _Pragma("unroll")                                                          \
    for (int i_ = 0; i_ < 8; ++i_) {                                           \
      acc[i_][J0] = __builtin_amdgcn_mfma_f32_16x16x32_bf16(AV[i_], B0V, acc[i_][J0], 0, 0, 0); \
      acc[i_][J1] = __builtin_amdgcn_mfma_f32_16x16x32_bf16(AV[i_], B1V, acc[i_][J1], 0, 0, 0); \
    }                                                                          \
    __builtin_amdgcn_s_setprio(0);                                             \
  } while (0)

#define LDS8(ofs) (*(const short8*)&lds[(ofs)])

  // fragment read offsets (shorts): phys chunk = (ks*4+hk) ^ (r0&7)
  const int swz = r0 & 7;
  const int ck0 = (hk ^ swz) * 8;          // ks = 0
  const int ck1 = ((hk ^ 4) ^ swz) * 8;    // ks = 1
  const int ar = (wr * 128 + r0) * 64;     // A row base (buf0; +16384 for buf1)
  const int br = 32768 + (wc * 64 + r0) * 64;  // B row base (buf0; +16384 for buf1)

  f32x4 acc[8][4];
#pragma unroll
  for (int i = 0; i < 8; ++i)
#pragma unroll
    for (int j = 0; j < 4; ++j) acc[i][j] = (f32x4)(0.f);

  // prologue: A(0)->A0, B(0)->B0, A(1)->A1  (6 stage-slots, 12 wave-loads)
  STAGE(gA, 0, 0, 0);     STAGE(gA, 0, 1, 0);
  STAGE(gB, 32768, 0, 0); STAGE(gB, 32768, 1, 0);
  STAGE(gA, 16384, 0, 1); STAGE(gA, 16384, 1, 1);
  __builtin_amdgcn_sched_barrier(0);
  asm volatile("s_waitcnt vmcnt(4)" ::: "memory");  // A0,B0 landed; A1 may fly
  __builtin_amdgcn_s_barrier();
  __builtin_amdgcn_sched_barrier(0);

#pragma unroll 1
  for (int t = 0; t < 8; ++t) {
    const int kt1 = 2 * t + 1;
    short8 av0[8], av1[8], bv[2], bw2[2];

    // ---- P1: read A0-ks0 (8) + B0 ks0 j0,1; stage B(2t+1)h0 -> B1
#pragma unroll
    for (int i_ = 0; i_ < 8; ++i_) av0[i_] = LDS8(ar + i_ * 1024 + ck0);
    bv[0] = LDS8(br + ck0);
    bv[1] = LDS8(br + 1024 + ck0);
    STAGE(gB, 49152, 0, kt1);
    PRE_MFMA_BARRIER();
    MFMA_BLK(av0, bv[0], bv[1], 0, 1);
    END_BARRIER();

    // ---- P2: read B0 ks0 j2,3 + A0-ks1 (8); stage B(2t+1)h1 -> B1
    bw2[0] = LDS8(br + 2048 + ck0);
    bw2[1] = LDS8(br + 3072 + ck0);
#pragma unroll
    for (int i_ = 0; i_ < 8; ++i_) av1[i_] = LDS8(ar + i_ * 1024 + ck1);
    STAGE(gB, 49152, 1, kt1);
    PRE_MFMA_BARRIER();
    MFMA_BLK(av0, bw2[0], bw2[1], 2, 3);
    END_BARRIER();

    // ---- P3: read B0 ks1 j0,1; stage A(2t+2)h0 -> A0
    bv[0] = LDS8(br + ck1);
    bv[1] = LDS8(br + 1024 + ck1);
    if (t < 7) STAGE(gA, 0, 0, 2 * t + 2);
    PRE_MFMA_BARRIER();
    MFMA_BLK(av1, bv[0], bv[1], 0, 1);
    END_BARRIER();

    // ---- P4: read B0 ks1 j2,3; stage A(2t+2)h1 -> A0; vmcnt wait
    bw2[0] = LDS8(br + 2048 + ck1);
    bw2[1] = LDS8(br + 3072 + ck1);
    if (t < 7) {
      STAGE(gA, 0, 1, 2 * t + 2);
      __builtin_amdgcn_sched_barrier(0);
      asm volatile("s_waitcnt vmcnt(4)" ::: "memory");  // B1(P1,P2) + older landed
    } else {
      __builtin_amdgcn_sched_barrier(0);
      asm volatile("s_waitcnt vmcnt(0)" ::: "memory");
    }
    PRE_MFMA_BARRIER();
    MFMA_BLK(av1, bw2[0], bw2[1], 2, 3);
    END_BARRIER();

    // ---- P5: read A1-ks0 (8) + B1 ks0 j0,1; stage B(2t+2)h0 -> B0
#pragma unroll
    for (int i_ = 0; i_ < 8; ++i_) av0[i_] = LDS8(16384 + ar + i_ * 1024 + ck0);
    bv[0] = LDS8(16384 + br + ck0);
    bv[1] = LDS8(16384 + br + 1024 + ck0);
    if (t < 7) STAGE(gB, 32768, 0, 2 * t + 2);
    PRE_MFMA_BARRIER();
    MFMA_BLK(av0, bv[0], bv[1], 0, 1);
    END_BARRIER();

    // ---- P6: read B1 ks0 j2,3 + A1-ks1 (8); stage B(2t+2)h1 -> B0
    bw2[0] = LDS8(16384 + br + 2048 + ck0);
    bw2[1] = LDS8(16384 + br + 3072 + ck0);
#pragma unroll
    for (int i_ = 0; i_ < 8; ++i_) av1[i_] = LDS8(16384 + ar + i_ * 1024 + ck1);
    if (t < 7) STAGE(gB, 32768, 1, 2 * t + 2);
    PRE_MFMA_BARRIER();
    MFMA_BLK(av0, bw2[0], bw2[1], 2, 3);
    END_BARRIER();

    // ---- P7: read B1 ks1 j0,1; stage A(2t+3)h0 -> A1
    bv[0] = LDS8(16384 + br + ck1);
    bv[1] = LDS8(16384 + br + 1024 + ck1);
    if (t < 7) STAGE(gA, 16384, 0, 2 * t + 3);
    PRE_MFMA_BARRIER();
    MFMA_BLK(av1, bv[0], bv[1], 0, 1);
    END_BARRIER();

    // ---- P8: read B1 ks1 j2,3; stage A(2t+3)h1 -> A1; vmcnt wait
    bw2[0] = LDS8(16384 + br + 2048 + ck1);
    bw2[1] = LDS8(16384 + br + 3072 + ck1);
    if (t < 7) {
      STAGE(gA, 16384, 1, 2 * t + 3);
      __builtin_amdgcn_sched_barrier(0);
      asm volatile("s_waitcnt vmcnt(4)" ::: "memory");  // B0(P5,P6) + older landed
    }
    PRE_MFMA_BARRIER();
    MFMA_BLK(av1, bw2[0], bw2[1], 2, 3);
    END_BARRIER();
  }
#undef STAGE
#undef PRE_MFMA_BARRIER
#undef END_BARRIER
#undef MFMA_BLK
#undef LDS8

  const int crow = m0 + wr * 128 + hk * 4;
  const int ccol = n0 + wc * 64 + r0;
  if (MODE == 0) {
    short* C = (short*)Cptr;
#pragma unroll
    for (int j = 0; j < 4; ++j) {
      float bj = bias[ccol + j * 16];
#pragma unroll
      for (int i = 0; i < 8; ++i) {
        size_t base = (size_t)(crow + i * 16) * N + (ccol + j * 16);
#pragma unroll
        for (int rr = 0; rr < 4; ++rr)
          C[base + (size_t)rr * N] = f2b(acc[i][j][rr] + bj);
      }
    }
  } else {
    float* C = (float*)Cptr;
#pragma unroll
    for (int j = 0; j < 4; ++j) {
      float bj = bias[ccol + j * 16];
#pragma unroll
      for (int i = 0; i < 8; ++i) {
        size_t base = (size_t)(crow + i * 16) * N + (ccol + j * 16);
#pragma unroll
        for (int rr = 0; rr < 4; ++rr)
          C[base + (size_t)rr * N] =
              acc[i][j][rr] + bj + resid[base + (size_t)rr * N];
      }
    }
  }
}

// ---------------- attention: 1 block per b, 4 waves, 2 heads/wave ----------------
__global__ __launch_bounds__(256) void attn_kernel(
    const short* __restrict__ qkv, const float* __restrict__ prior,
    const float* __restrict__ mask, short* __restrict__ out) {
  __shared__ short sq[8 * 3080];  // rows padded +8 shorts to break bank conflicts
  const int tid = threadIdx.x;
  const int b = blockIdx.x;
  for (int c = tid; c < 3072; c += 256) {
    int row = c / 384;
    int cc = c - row * 384;
    *(short8*)&sq[row * 3080 + cc * 8] =
        *(const short8*)&qkv[((size_t)b * 8 + row) * 3072 + cc * 8];
  }
  __syncthreads();
  const int l = tid & 63, w = tid >> 6;
  const int i = l >> 3, j = l & 7;
  const float pv = prior[l];
  const float mm = mask[b * 8 + i] * mask[b * 8 + j];
#pragma unroll
  for (int hh = 0; hh < 2; ++hh) {
    const int h = w + hh * 4;
    const short* Qr = &sq[i * 3080 + h * 128];
    const short* Kr = &sq[j * 3080 + 1024 + h * 128];
    float s = 0.f;
#pragma unroll
    for (int c = 0; c < 16; ++c) {
      short8 qa = *(const short8*)&Qr[c * 8];
      short8 ka = *(const short8*)&Kr[c * 8];
#pragma unroll
      for (int e = 0; e < 8; ++e) s += bf2f(qa[e]) * bf2f(ka[e]);
    }
    s = s * 0.08838834764831843f + pv;  // 1/sqrt(128)
    if (!(mm > 0.f)) s = -__builtin_inff();
    float mx = s;
#pragma unroll
    for (int off = 1; off < 8; off <<= 1) mx = fmaxf(mx, __shfl_xor(mx, off));
    float e = __expf(s - mx);
    float sum = e;
#pragma unroll
    for (int off = 1; off < 8; off <<= 1) sum += __shfl_xor(sum, off);
    float p = e / sum;
    float o[16];
#pragma unroll
    for (int t = 0; t < 16; ++t) o[t] = 0.f;
#pragma unroll
    for (int jj = 0; jj < 8; ++jj) {
      float pj = __shfl(p, i * 8 + jj);
      const short* Vr = &sq[jj * 3080 + 2048 + h * 128 + j * 16];
      short8 v0 = *(const short8*)&Vr[0];
      short8 v1 = *(const short8*)&Vr[8];
#pragma unroll
      for (int e2 = 0; e2 < 8; ++e2) {
        o[e2] += pj * bf2f(v0[e2]);
        o[8 + e2] += pj * bf2f(v1[e2]);
      }
    }
    short8 o0, o1;
#pragma unroll
    for (int e2 = 0; e2 < 8; ++e2) { o0[e2] = f2b(o[e2]); o1[e2] = f2b(o[8 + e2]); }
    short* dst = out + ((size_t)(b * 8 + i)) * 1024 + h * 128 + j * 16;
    *(short8*)dst = o0;
    *(short8*)(dst + 8) = o1;
  }
}

// ---------------- LayerNorm in-place, 1 wave per row ----------------
__global__ __launch_bounds__(256) void ln_kernel(float* __restrict__ io,
                                                 const float* __restrict__ gamma,
                                                 const float* __restrict__ beta) {
  const int l = threadIdx.x & 63, w = threadIdx.x >> 6;
  float* p = io + ((size_t)blockIdx.x * 4 + w) * 1024;
  f32x4 v[4];
  float s = 0.f;
#pragma unroll
  for (int c = 0; c < 4; ++c) {
    v[c] = *(const f32x4*)(p + (c * 64 + l) * 4);
    s += v[c][0] + v[c][1] + v[c][2] + v[c][3];
  }
#pragma unroll
  for (int off = 32; off > 0; off >>= 1) s += __shfl_xor(s, off);
  const float mu = s * (1.f / 1024.f);
  float s2 = 0.f;
#pragma unroll
  for (int c = 0; c < 4; ++c)
#pragma unroll
    for (int e = 0; e < 4; ++e) { float d = v[c][e] - mu; s2 += d * d; }
#pragma unroll
  for (int off = 32; off > 0; off >>= 1) s2 += __shfl_xor(s2, off);
  const float rstd = rsqrtf(s2 * (1.f / 1024.f) + LN_EPS);
#pragma unroll
  for (int c = 0; c < 4; ++c) {
    f32x4 g = *(const f32x4*)(gamma + (c * 64 + l) * 4);
    f32x4 bt = *(const f32x4*)(beta + (c * 64 + l) * 4);
    f32x4 ov;
#pragma unroll
    for (int e = 0; e < 4; ++e) ov[e] = (v[c][e] - mu) * rstd * g[e] + bt[e];
    *(f32x4*)(p + (c * 64 + l) * 4) = ov;
  }
}

extern "C" void kernel_launch(void* const* d_in, const int* in_sizes, int n_in,
                              void* d_out, int out_size, void* d_ws, size_t ws_size,
                              hipStream_t stream) {
  const float* x     = (const float*)d_in[0];
  const float* mask  = (const float*)d_in[1];
  const float* wq    = (const float*)d_in[2];
  const float* bq    = (const float*)d_in[3];
  const float* wk    = (const float*)d_in[4];
  const float* bk    = (const float*)d_in[5];
  const float* wv    = (const float*)d_in[6];
  const float* bv    = (const float*)d_in[7];
  const float* wo    = (const float*)d_in[8];
  const float* bo    = (const float*)d_in[9];
  const float* prior = (const float*)d_in[10];
  const float* gamma = (const float*)d_in[11];
  const float* beta  = (const float*)d_in[12];

  char* ws = (char*)d_ws;
  short* qkv  = (short*)(ws);                    // [65536][3072] bf16 (402.7 MB)
  short* xb   = (short*)(ws + 402653184L);       // [65536][1024] bf16; reused as attn_out
  short* wall = (short*)(ws + 536870912L);       // [3072][1024] bf16 (Wq|Wk|Wv)
  short* wob  = (short*)(ws + 543162368L);       // [1024][1024] bf16
  float* ball = (float*)(ws + 545259520L);       // [3072] f32

  cvt_kernel<<<2048, 256, 0, stream>>>(x, xb, 8388608);
  cvt_kernel<<<512, 256, 0, stream>>>(wq, wall,           131072);
  cvt_kernel<<<512, 256, 0, stream>>>(wk, wall + 1048576, 131072);
  cvt_kernel<<<512, 256, 0, stream>>>(wv, wall + 2097152, 131072);
  cvt_kernel<<<512, 256, 0, stream>>>(wo, wob,            131072);
  pack_bias<<<4, 256, 0, stream>>>(bq, bk, bv, ball);

  // QKV projection: [65536,3072] = xb @ Wall^T + ball   (256x12 = 3072 blocks)
  gemm256<0><<<3072, 512, 0, stream>>>(xb, wall, ball, nullptr, qkv, 3072);
  // attention (writes into xb, free after QKV GEMM)
  attn_kernel<<<8192, 256, 0, stream>>>(qkv, prior, mask, xb);
  // O projection + bias + residual -> d_out (f32)   (256x4 = 1024 blocks)
  gemm256<1><<<1024, 512, 0, stream>>>(xb, wob, bo, x, d_out, 1024);
  // LayerNorm in-place on d_out
  ln_kernel<<<16384, 256, 0, stream>>>((float*)d_out, gamma, beta);
}

// Round 6
// 1041.863 us; speedup vs baseline: 1.4546x; 1.4546x over previous
//
#include <hip/hip_runtime.h>

typedef __attribute__((ext_vector_type(4))) float f32x4;
typedef __attribute__((ext_vector_type(8))) short short8;

#define LN_EPS 1e-5f

__device__ __forceinline__ float bf2f(short x) {
  union { unsigned u; float f; } c;
  c.u = ((unsigned)(unsigned short)x) << 16;
  return c.f;
}
__device__ __forceinline__ short f2b(float f) {
  union { float f; unsigned u; } c; c.f = f;
  unsigned r = (c.u + 0x7fffu + ((c.u >> 16) & 1u)) >> 16;
  return (short)r;
}

// ---------------- f32 -> bf16 convert (8 elems / thread) ----------------
__global__ __launch_bounds__(256) void cvt_kernel(const float* __restrict__ src,
                                                  short* __restrict__ dst, int n8) {
  int idx = blockIdx.x * 256 + threadIdx.x;
  int stride = gridDim.x * 256;
  for (int c = idx; c < n8; c += stride) {
    const f32x4* s = (const f32x4*)(src + (size_t)c * 8);
    f32x4 v0 = s[0], v1 = s[1];
    short8 o;
    o[0] = f2b(v0.x); o[1] = f2b(v0.y); o[2] = f2b(v0.z); o[3] = f2b(v0.w);
    o[4] = f2b(v1.x); o[5] = f2b(v1.y); o[6] = f2b(v1.z); o[7] = f2b(v1.w);
    *(short8*)(dst + (size_t)c * 8) = o;
  }
}

__global__ __launch_bounds__(256) void pack_bias(const float* __restrict__ bq,
                                                 const float* __restrict__ bk,
                                                 const float* __restrict__ bv,
                                                 float* __restrict__ dst) {
  int t = blockIdx.x * 256 + threadIdx.x;
  if (t < 1024) { dst[t] = bq[t]; dst[1024 + t] = bk[t]; dst[2048 + t] = bv[t]; }
}

__device__ __forceinline__ void gload16(const short* g, const short* l) {
  __builtin_amdgcn_global_load_lds((const __attribute__((address_space(1))) unsigned int*)g,
                                   (__attribute__((address_space(3))) unsigned int*)l,
                                   16, 0, 0);
}

// ---------------- GEMM: C[M,N] = A[M,1024] * W[N,1024]^T (+ epilogue) ----------------
// 256x256 tile, BK=32, 32 K-tiles. 512 threads (8 waves 2Mx4N), per-wave out 128x64.
// LDS ring of 4 slots (A 16KB + B 16KB each) = 128 KB. ONE barrier + ONE counted
// vmcnt(8) per K-tile; register-pipelined A-fragments (read tile t+1 while MFMA of
// tile t runs) take LDS reads off the critical path. lgkmcnt(0) at iter top drains
// last iter's reads (free) making the slot-reuse ledger airtight.
// Swizzle (64B rows): phys 16B-chunk = logical ^ ((row>>1)&3); inverse on global src.
template <int MODE>  // 0: out bf16 ldc=N, bias   1: out f32 ldc=N, bias+resid
__global__ __launch_bounds__(512, 2) void gemm256(
    const short* __restrict__ A, const short* __restrict__ W,
    const float* __restrict__ bias, const float* __restrict__ resid,
    void* __restrict__ Cptr, int N) {
  __shared__ __align__(16) short lds[65536];  // slot s: A at s*16384, B at s*16384+8192

  const int tid = threadIdx.x;
  const int w = tid >> 6, l = tid & 63;
  const int wr = w >> 2, wc = w & 3;
  const int r0 = l & 15, hk = l >> 4;

  // XCD swizzle (grid % 8 == 0 here)
  const int q8 = gridDim.x >> 3;
  const int wg = (blockIdx.x & 7) * q8 + (blockIdx.x >> 3);
  const int nbx = N >> 8;
  const int mb = wg / nbx, nb = wg - mb * nbx;
  const int m0 = mb << 8, n0 = nb << 8;

  // staging: per K-tile A = 256 rows x 32 shorts = 1024 16B-chunks; thread covers
  // chunk tid (rows 0..127) and tid+512 (rows 128..255); same for B.
  const int srow = tid >> 2;                                  // 0..127
  const int lcol = (((tid & 3) ^ ((srow >> 1) & 3)) << 3);    // inv-swizzled col (shorts)
  const short* gA1 = A + (size_t)(m0 + srow) * 1024 + lcol;
  const short* gA2 = gA1 + 131072;   // +128 rows
  const short* gB1 = W + (size_t)(n0 + srow) * 1024 + lcol;
  const short* gB2 = gB1 + 131072;
  const int wofs = w * 512;  // wave-uniform LDS dest (shorts); lane*16B added by HW

#define STAGE(KT) do { const int sl_ = ((KT) & 3) * 16384, ko_ = (KT) * 32;  \
    gload16(gA1 + ko_, &lds[sl_ + wofs]);                                    \
    gload16(gA2 + ko_, &lds[sl_ + 4096 + wofs]);                             \
    gload16(gB1 + ko_, &lds[sl_ + 8192 + wofs]);                             \
    gload16(gB2 + ko_, &lds[sl_ + 12288 + wofs]); } while (0)

  // fragment read offsets (shorts): phys chunk = hk ^ ((r0>>1)&3)
  const int pc = (hk ^ ((r0 >> 1) & 3)) << 3;
  const int ar = (wr * 128 + r0) * 32 + pc;        // + i*512 per 16-row step
  const int br = 8192 + (wc * 64 + r0) * 32 + pc;  // + j*512

#define LOAD_A(KT, AV) do { const int sb_ = ((KT) & 3) * 16384;              \
    _Pragma("unroll")                                                        \
    for (int i_ = 0; i_ < 8; ++i_)                                           \
      AV[i_] = *(const short8*)&lds[sb_ + ar + i_ * 512]; } while (0)

#define LOAD_B(KT, BV) do { const int sb_ = ((KT) & 3) * 16384;              \
    _Pragma("unroll")                                                        \
    for (int j_ = 0; j_ < 4; ++j_)                                           \
      BV[j_] = *(const short8*)&lds[sb_ + br + j_ * 512]; } while (0)

#define DOMFMA(AV, BV) do { __builtin_amdgcn_s_setprio(1);                   \
    _Pragma("unroll")                                                        \
    for (int i_ = 0; i_ < 8; ++i_)                                           \
      _Pragma("unroll")                                                      \
      for (int j_ = 0; j_ < 4; ++j_)                                         \
        acc[i_][j_] = __builtin_amdgcn_mfma_f32_16x16x32_bf16(AV[i_], BV[j_], acc[i_][j_], 0, 0, 0); \
    __builtin_amdgcn_s_setprio(0); } while (0)

  // iter T: drain lgkm; stage T+3; vmcnt(8); barrier (publishes T+1); read B(T) +
  // A-frags(T+1) into NA; MFMA(T) with CA. (B single-buffered: 4 reads, hidden.)
#define ITER(T, CA, NA) do {                                                 \
    asm volatile("s_waitcnt lgkmcnt(0)" ::: "memory");                       \
    if ((T) < 29) { STAGE((T) + 3);                                          \
      asm volatile("s_waitcnt vmcnt(8)" ::: "memory"); }                     \
    else if ((T) == 29) { asm volatile("s_waitcnt vmcnt(4)" ::: "memory"); } \
    else { asm volatile("s_waitcnt vmcnt(0)" ::: "memory"); }                \
    __builtin_amdgcn_s_barrier();                                            \
    __builtin_amdgcn_sched_barrier(0);                                       \
    LOAD_B((T), bv);                                                         \
    if ((T) < 31) LOAD_A((T) + 1, NA);                                       \
    DOMFMA(CA, bv);                                                          \
  } while (0)

  f32x4 acc[8][4];
#pragma unroll
  for (int i = 0; i < 8; ++i)
#pragma unroll
    for (int j = 0; j < 4; ++j) acc[i][j] = (f32x4)(0.f);

  short8 av0[8], av1[8], bv[4];

  // prologue: stage tiles 0,1,2; wait tile 0; read A-frags(0)
  STAGE(0); STAGE(1); STAGE(2);
  asm volatile("s_waitcnt vmcnt(8)" ::: "memory");
  __builtin_amdgcn_s_barrier();
  __builtin_amdgcn_sched_barrier(0);
  LOAD_A(0, av0);

#pragma unroll 1
  for (int u = 0; u < 16; ++u) {
    ITER(2 * u,     av0, av1);
    ITER(2 * u + 1, av1, av0);
  }
#undef STAGE
#undef LOAD_A
#undef LOAD_B
#undef DOMFMA
#undef ITER

  const int crow = m0 + wr * 128 + hk * 4;
  const int ccol = n0 + wc * 64 + r0;
  if (MODE == 0) {
    short* C = (short*)Cptr;
#pragma unroll
    for (int j = 0; j < 4; ++j) {
      float bj = bias[ccol + j * 16];
#pragma unroll
      for (int i = 0; i < 8; ++i) {
        size_t base = (size_t)(crow + i * 16) * N + (ccol + j * 16);
#pragma unroll
        for (int rr = 0; rr < 4; ++rr)
          C[base + (size_t)rr * N] = f2b(acc[i][j][rr] + bj);
      }
    }
  } else {
    float* C = (float*)Cptr;
#pragma unroll
    for (int j = 0; j < 4; ++j) {
      float bj = bias[ccol + j * 16];
#pragma unroll
      for (int i = 0; i < 8; ++i) {
        size_t base = (size_t)(crow + i * 16) * N + (ccol + j * 16);
#pragma unroll
        for (int rr = 0; rr < 4; ++rr)
          C[base + (size_t)rr * N] =
              acc[i][j][rr] + bj + resid[base + (size_t)rr * N];
      }
    }
  }
}

// ---------------- attention: 1 block per b, 4 waves, 2 heads/wave ----------------
__global__ __launch_bounds__(256) void attn_kernel(
    const short* __restrict__ qkv, const float* __restrict__ prior,
    const float* __restrict__ mask, short* __restrict__ out) {
  __shared__ short sq[8 * 3080];  // rows padded +8 shorts to break bank conflicts
  const int tid = threadIdx.x;
  const int b = blockIdx.x;
  for (int c = tid; c < 3072; c += 256) {
    int row = c / 384;
    int cc = c - row * 384;
    *(short8*)&sq[row * 3080 + cc * 8] =
        *(const short8*)&qkv[((size_t)b * 8 + row) * 3072 + cc * 8];
  }
  __syncthreads();
  const int l = tid & 63, w = tid >> 6;
  const int i = l >> 3, j = l & 7;
  const float pv = prior[l];
  const float mm = mask[b * 8 + i] * mask[b * 8 + j];
#pragma unroll
  for (int hh = 0; hh < 2; ++hh) {
    const int h = w + hh * 4;
    const short* Qr = &sq[i * 3080 + h * 128];
    const short* Kr = &sq[j * 3080 + 1024 + h * 128];
    float s = 0.f;
#pragma unroll
    for (int c = 0; c < 16; ++c) {
      short8 qa = *(const short8*)&Qr[c * 8];
      short8 ka = *(const short8*)&Kr[c * 8];
#pragma unroll
      for (int e = 0; e < 8; ++e) s += bf2f(qa[e]) * bf2f(ka[e]);
    }
    s = s * 0.08838834764831843f + pv;  // 1/sqrt(128)
    if (!(mm > 0.f)) s = -__builtin_inff();
    float mx = s;
#pragma unroll
    for (int off = 1; off < 8; off <<= 1) mx = fmaxf(mx, __shfl_xor(mx, off));
    float e = __expf(s - mx);
    float sum = e;
#pragma unroll
    for (int off = 1; off < 8; off <<= 1) sum += __shfl_xor(sum, off);
    float p = e / sum;
    float o[16];
#pragma unroll
    for (int t = 0; t < 16; ++t) o[t] = 0.f;
#pragma unroll
    for (int jj = 0; jj < 8; ++jj) {
      float pj = __shfl(p, i * 8 + jj);
      const short* Vr = &sq[jj * 3080 + 2048 + h * 128 + j * 16];
      short8 v0 = *(const short8*)&Vr[0];
      short8 v1 = *(const short8*)&Vr[8];
#pragma unroll
      for (int e2 = 0; e2 < 8; ++e2) {
        o[e2] += pj * bf2f(v0[e2]);
        o[8 + e2] += pj * bf2f(v1[e2]);
      }
    }
    short8 o0, o1;
#pragma unroll
    for (int e2 = 0; e2 < 8; ++e2) { o0[e2] = f2b(o[e2]); o1[e2] = f2b(o[8 + e2]); }
    short* dst = out + ((size_t)(b * 8 + i)) * 1024 + h * 128 + j * 16;
    *(short8*)dst = o0;
    *(short8*)(dst + 8) = o1;
  }
}

// ---------------- LayerNorm in-place, 1 wave per row ----------------
__global__ __launch_bounds__(256) void ln_kernel(float* __restrict__ io,
                                                 const float* __restrict__ gamma,
                                                 const float* __restrict__ beta) {
  const int l = threadIdx.x & 63, w = threadIdx.x >> 6;
  float* p = io + ((size_t)blockIdx.x * 4 + w) * 1024;
  f32x4 v[4];
  float s = 0.f;
#pragma unroll
  for (int c = 0; c < 4; ++c) {
    v[c] = *(const f32x4*)(p + (c * 64 + l) * 4);
    s += v[c][0] + v[c][1] + v[c][2] + v[c][3];
  }
#pragma unroll
  for (int off = 32; off > 0; off >>= 1) s += __shfl_xor(s, off);
  const float mu = s * (1.f / 1024.f);
  float s2 = 0.f;
#pragma unroll
  for (int c = 0; c < 4; ++c)
#pragma unroll
    for (int e = 0; e < 4; ++e) { float d = v[c][e] - mu; s2 += d * d; }
#pragma unroll
  for (int off = 32; off > 0; off >>= 1) s2 += __shfl_xor(s2, off);
  const float rstd = rsqrtf(s2 * (1.f / 1024.f) + LN_EPS);
#pragma unroll
  for (int c = 0; c < 4; ++c) {
    f32x4 g = *(const f32x4*)(gamma + (c * 64 + l) * 4);
    f32x4 bt = *(const f32x4*)(beta + (c * 64 + l) * 4);
    f32x4 ov;
#pragma unroll
    for (int e = 0; e < 4; ++e) ov[e] = (v[c][e] - mu) * rstd * g[e] + bt[e];
    *(f32x4*)(p + (c * 64 + l) * 4) = ov;
  }
}

extern "C" void kernel_launch(void* const* d_in, const int* in_sizes, int n_in,
                              void* d_out, int out_size, void* d_ws, size_t ws_size,
                              hipStream_t stream) {
  const float* x     = (const float*)d_in[0];
  const float* mask  = (const float*)d_in[1];
  const float* wq    = (const float*)d_in[2];
  const float* bq    = (const float*)d_in[3];
  const float* wk    = (const float*)d_in[4];
  const float* bk    = (const float*)d_in[5];
  const float* wv    = (const float*)d_in[6];
  const float* bv    = (const float*)d_in[7];
  const float* wo    = (const float*)d_in[8];
  const float* bo    = (const float*)d_in[9];
  const float* prior = (const float*)d_in[10];
  const float* gamma = (const float*)d_in[11];
  const float* beta  = (const float*)d_in[12];

  char* ws = (char*)d_ws;
  short* qkv  = (short*)(ws);                    // [65536][3072] bf16 (402.7 MB)
  short* xb   = (short*)(ws + 402653184L);       // [65536][1024] bf16; reused as attn_out
  short* wall = (short*)(ws + 536870912L);       // [3072][1024] bf16 (Wq|Wk|Wv)
  short* wob  = (short*)(ws + 543162368L);       // [1024][1024] bf16
  float* ball = (float*)(ws + 545259520L);       // [3072] f32

  cvt_kernel<<<2048, 256, 0, stream>>>(x, xb, 8388608);
  cvt_kernel<<<512, 256, 0, stream>>>(wq, wall,           131072);
  cvt_kernel<<<512, 256, 0, stream>>>(wk, wall + 1048576, 131072);
  cvt_kernel<<<512, 256, 0, stream>>>(wv, wall + 2097152, 131072);
  cvt_kernel<<<512, 256, 0, stream>>>(wo, wob,            131072);
  pack_bias<<<4, 256, 0, stream>>>(bq, bk, bv, ball);

  // QKV projection: [65536,3072] = xb @ Wall^T + ball   (256x12 = 3072 blocks)
  gemm256<0><<<3072, 512, 0, stream>>>(xb, wall, ball, nullptr, qkv, 3072);
  // attention (writes into xb, free after QKV GEMM)
  attn_kernel<<<8192, 256, 0, stream>>>(qkv, prior, mask, xb);
  // O projection + bias + residual -> d_out (f32)   (256x4 = 1024 blocks)
  gemm256<1><<<1024, 512, 0, stream>>>(xb, wob, bo, x, d_out, 1024);
  // LayerNorm in-place on d_out
  ln_kernel<<<16384, 256, 0, stream>>>((float*)d_out, gamma, beta);
}